// Round 7
// baseline (235.374 us; speedup 1.0000x reference)
//
#include <hip/hip_runtime.h>
#include <stdint.h>

#define IN_F   8192
#define OUT_F  8192
#define MB     64
#define RANK   16
#define KSPLIT 4

typedef _Float16 f16x8 __attribute__((ext_vector_type(8)));
typedef _Float16 f16x2 __attribute__((ext_vector_type(2)));
typedef float    f32x4 __attribute__((ext_vector_type(4)));

__device__ __forceinline__ unsigned pk2h(float a, float b) {
    return __builtin_bit_cast(unsigned, __builtin_amdgcn_cvt_pkrtz(a, b));
}

// Decode 8 nvfp4 codes (dword p) -> f16x8 scaled by s2 (packed f16 pair).
// v_perm hi-byte LUT + sign bit3<<4. Verified across prior rounds.
__device__ __forceinline__ f16x8 decode8(unsigned p, unsigned s2) {
    unsigned q  = p >> 4;
    unsigned me = __builtin_amdgcn_perm(0x46444240u, 0x3E3C3800u, p & 0x07070707u);
    unsigned mo = __builtin_amdgcn_perm(0x46444240u, 0x3E3C3800u, q & 0x07070707u);
    unsigned he = ((p & 0x08080808u) << 4) | me;
    unsigned ho = ((q & 0x08080808u) << 4) | mo;
    unsigned bu0 = __builtin_amdgcn_perm(ho, he, 0x040C000Cu);
    unsigned bu1 = __builtin_amdgcn_perm(ho, he, 0x050C010Cu);
    unsigned bu2 = __builtin_amdgcn_perm(ho, he, 0x060C020Cu);
    unsigned bu3 = __builtin_amdgcn_perm(ho, he, 0x070C030Cu);
    f16x2 sv = __builtin_bit_cast(f16x2, s2);
    f16x2 h0 = __builtin_bit_cast(f16x2, bu0) * sv;
    f16x2 h1 = __builtin_bit_cast(f16x2, bu1) * sv;
    f16x2 h2 = __builtin_bit_cast(f16x2, bu2) * sv;
    f16x2 h3 = __builtin_bit_cast(f16x2, bu3) * sv;
    f16x8 b;
    b[0]=h0[0]; b[1]=h0[1]; b[2]=h1[0]; b[3]=h1[1];
    b[4]=h2[0]; b[5]=h2[1]; b[6]=h3[0]; b[7]=h3[1];
    return b;
}

// pack 4 source dwords (low byte each) -> 1 packed dword [b0(x),b0(y),b0(z),b0(w)]
__device__ __forceinline__ unsigned pack4(uint4 a) {
    unsigned t0 = __builtin_amdgcn_perm(a.y, a.x, 0x0C0C0400u);
    unsigned t1 = __builtin_amdgcn_perm(a.w, a.z, 0x0C0C0400u);
    return __builtin_amdgcn_perm(t1, t0, 0x05040100u);
}

// ---------------------------------------------------------------------------
// prep: grid (64 m, 4 kq). x quarter -> MFMA-A-fragment layout; t partials
// written per-kq (no atomics, no zero-init dependency on poisoned ws).
// ---------------------------------------------------------------------------
__global__ __launch_bounds__(256) void prep_kernel(
    const float* __restrict__ x, const float* __restrict__ lora_A,
    uint2* __restrict__ xf2, float* __restrict__ tp)
{
    const int m = blockIdx.x, kq = blockIdx.y;
    const int tid = threadIdx.x;
    const int mt = m >> 4, l15 = m & 15;
    float acc[RANK];
#pragma unroll
    for (int r = 0; r < RANK; ++r) acc[r] = 0.f;

    const float4* x4 = (const float4*)(x + (size_t)m * IN_F);
    const float4* A4 = (const float4*)lora_A;
#pragma unroll
    for (int it = 0; it < 2; ++it) {
        int j = kq * 512 + it * 256 + tid;
        float4 xv = x4[j];
        uint2 u;
        u.x = pk2h(xv.x, xv.y);
        u.y = pk2h(xv.z, xv.w);
        int kstep = j >> 3, quad = (j >> 1) & 3, h = j & 1;
        xf2[(size_t)(((kstep * 4 + mt) * 64 + quad * 16 + l15) * 2 + h)] = u;
#pragma unroll
        for (int r = 0; r < RANK; ++r) {
            float4 av = A4[(size_t)r * (IN_F / 4) + j];
            acc[r] += xv.x * av.x + xv.y * av.y + xv.z * av.z + xv.w * av.w;
        }
    }
#pragma unroll
    for (int r = 0; r < RANK; ++r)
#pragma unroll
        for (int off = 32; off > 0; off >>= 1)
            acc[r] += __shfl_down(acc[r], off);

    __shared__ float red[4][RANK];
    int lane = tid & 63, wid = tid >> 6;
    if (lane == 0) {
#pragma unroll
        for (int r = 0; r < RANK; ++r) red[wid][r] = acc[r];
    }
    __syncthreads();
    if (tid < RANK)
        tp[((size_t)kq * MB + m) * RANK + tid] =
            red[0][tid] + red[1][tid] + red[2][tid] + red[3][tid];
}

__device__ __forceinline__ float4 lora4(const float* __restrict__ tp, int m,
                                        const float* __restrict__ lora_B, int n4) {
    float ta[RANK];
#pragma unroll
    for (int r = 0; r < RANK; ++r) ta[r] = 0.f;
#pragma unroll
    for (int kq = 0; kq < 4; ++kq) {
        const float4* t4 = (const float4*)(tp + ((size_t)kq * MB + m) * RANK);
#pragma unroll
        for (int i = 0; i < 4; ++i) {
            float4 v = t4[i];
            ta[4*i+0] += v.x; ta[4*i+1] += v.y; ta[4*i+2] += v.z; ta[4*i+3] += v.w;
        }
    }
    float4 o;
    float* op = (float*)&o;
#pragma unroll
    for (int j = 0; j < 4; ++j) {
        const float4* B4 = (const float4*)(lora_B + (size_t)(n4 + j) * RANK);
        float s = 0.f;
#pragma unroll
        for (int i = 0; i < 4; ++i) {
            float4 b = B4[i];
            s += ta[4*i+0]*b.x + ta[4*i+1]*b.y + ta[4*i+2]*b.z + ta[4*i+3]*b.w;
        }
        op[j] = s;
    }
    return o;
}

__global__ __launch_bounds__(256) void lora_kernel(
    const float* __restrict__ tp, const float* __restrict__ lora_B,
    float* __restrict__ out)
{
    const int gid = blockIdx.x * 256 + threadIdx.x;
    ((float4*)out)[gid] = lora4(tp, gid >> 11, lora_B, (gid & 2047) * 4);
}

__global__ __launch_bounds__(256) void finish_kernel(
    const float* __restrict__ partial, const float* __restrict__ tp,
    const float* __restrict__ lora_B, float* __restrict__ out)
{
    const int gid = blockIdx.x * 256 + threadIdx.x;
    float4 p = {0.f, 0.f, 0.f, 0.f};
#pragma unroll
    for (int ksp = 0; ksp < KSPLIT; ++ksp) {
        float4 v = ((const float4*)partial)[(size_t)ksp * (MB * OUT_F / 4) + gid];
        p.x += v.x; p.y += v.y; p.z += v.z; p.w += v.w;
    }
    float4 l = lora4(tp, gid >> 11, lora_B, (gid & 2047) * 4);
    p.x += l.x; p.y += l.y; p.z += l.z; p.w += l.w;
    ((float4*)out)[gid] = p;
}

// ---------------------------------------------------------------------------
// main8: fused repack + GEMM + dequant.
// grid (KSPLIT=4, 128) = 512 blocks = 2/CU (80 KiB LDS), block 256 = 4 waves.
// Block: 64 n-rows x 64 m x 2048 k, looped as 4 chunks of 512 k; wave owns
// 16 rows (nt=1). Per chunk:
//   - xs (64 KiB x fragments) re-staged from L2-resident xf (2 barriers).
//   - W staged wave-private: 16 loads, each 1 KiB CONTIGUOUS (64 lanes x 16B
//     on one row) -> full-line full-page bursts; packed in-register (pack4),
//     written to a 4 KiB/wave XOR-swizzled LDS tile (<=2-way = free).
//   - W loads + scale loads for chunk c+1 issue BEFORE compute(c).
// No manual vmcnt (R2 lesson), no barriers around wave-private W.
// KSPLIT=4 -> partial is 8 MiB (was 32): -48 MiB round-trip traffic.
// ---------------------------------------------------------------------------
template<int ATOMIC>
__global__ __launch_bounds__(256, 2) void main8_kernel(
    const void*  __restrict__ Wpv,
    const float* __restrict__ scales,
    const uint4* __restrict__ xf4,
    float*       __restrict__ dst)
{
    __shared__ __align__(16) uint4    xs[4096];        // 64 KiB x fragments
    __shared__ __align__(16) unsigned wlds[4][16][64]; // 16 KiB packed W

    const int tid = threadIdx.x;
    const int lane = tid & 63, w = tid >> 6;
    const int l15 = lane & 15, quad = lane >> 4, qh = quad >> 1;
    const int ksp = blockIdx.x, nb = blockIdx.y * 64;
    const int nrow = nb + w * 16 + l15;     // this lane's output column n

    // format detect (wave-uniform, L2-broadcast)
    unsigned dv = ((const unsigned*)Wpv)[lane];
    const bool fmt1 = (__ballot(dv > 255u) == 0ull);

    const uint4* Wp4 = (const uint4*)Wpv;
    uint4 rg[16];
    unsigned sreg[2][16];

    // LOADW chunk kcn: wave's 16 rows x 64 packed dwords. fmt1: 16 insts,
    // each 1 KiB contiguous (64 lanes x 16 B, one row). fmt0: 4 insts,
    // each 4 rows x 256 B contiguous.
#define LOADW(kcn)                                                            \
    do {                                                                      \
        if (fmt1) {                                                           \
            const size_t b1 = (size_t)ksp * 256 + (kcn) * 64 + lane;          \
            _Pragma("unroll") for (int r = 0; r < 16; ++r)                    \
                rg[r] = Wp4[(size_t)(nb + w * 16 + r) * 1024 + b1];           \
        } else {                                                              \
            const size_t b0 = (size_t)ksp * 64 + (kcn) * 16 + (lane & 15);    \
            _Pragma("unroll") for (int i = 0; i < 4; ++i)                     \
                rg[i] = Wp4[(size_t)(nb + w * 16 + i * 4 + (lane >> 4)) * 256 \
                            + b0];                                            \
        }                                                                     \
    } while (0)

    // WRITEW: wave-private swizzled tile. fmt1: lane = pd_local = s*4+quad.
#define WRITEW()                                                              \
    do {                                                                      \
        if (fmt1) {                                                           \
            _Pragma("unroll") for (int r = 0; r < 16; ++r)                    \
                wlds[w][r][lane ^ ((r & 7) << 2)] = pack4(rg[r]);             \
        } else {                                                              \
            _Pragma("unroll") for (int i = 0; i < 4; ++i) {                   \
                int r = i * 4 + (lane >> 4), c16 = lane & 15;                 \
                *(uint4*)&wlds[w][r][(c16 * 4) ^ ((r & 7) << 2)] = rg[i];     \
            }                                                                 \
        }                                                                     \
    } while (0)

    // scales for chunk kcn -> sreg[kcn&1] (per-lane row, qh parity select)
#define SREGLOAD(kcn)                                                         \
    do {                                                                      \
        const float4* sp = (const float4*)(scales + (size_t)nrow * (IN_F/16)  \
                                           + ksp * 128 + (kcn) * 32);         \
        _Pragma("unroll") for (int i = 0; i < 8; ++i) {                       \
            float4 vv = sp[i];                                                \
            float a = qh ? vv.y : vv.x, b = qh ? vv.w : vv.z;                 \
            sreg[(kcn) & 1][2 * i]     = pk2h(a, a);                          \
            sreg[(kcn) & 1][2 * i + 1] = pk2h(b, b);                          \
        }                                                                     \
    } while (0)

    // xs re-stage for chunk kcn (two reg-staged half passes, 8 KiB/thread-grp)
#define XSTAGE(kcn)                                                           \
    do {                                                                      \
        const uint4* gsrc = xf4 + (size_t)(ksp * 64 + (kcn) * 16) * 256;      \
        uint4 xr[8];                                                          \
        _Pragma("unroll") for (int j = 0; j < 8; ++j)                         \
            xr[j] = gsrc[j * 256 + tid];                                      \
        _Pragma("unroll") for (int j = 0; j < 8; ++j)                         \
            xs[j * 256 + tid] = xr[j];                                        \
        _Pragma("unroll") for (int j = 0; j < 8; ++j)                         \
            xr[j] = gsrc[2048 + j * 256 + tid];                               \
        _Pragma("unroll") for (int j = 0; j < 8; ++j)                         \
            xs[2048 + j * 256 + tid] = xr[j];                                 \
    } while (0)

#define COMPUTE(kcn)                                                          \
    do {                                                                      \
        const int swzl = (l15 & 7) << 2;                                      \
        _Pragma("unroll") for (int s = 0; s < 16; ++s) {                      \
            f16x8 afr[4];                                                     \
            _Pragma("unroll") for (int mt = 0; mt < 4; ++mt)                  \
                afr[mt] = __builtin_bit_cast(f16x8, xs[(s*4+mt)*64 + lane]);  \
            unsigned p = wlds[w][l15][(s * 4 + quad) ^ swzl];                 \
            f16x8 b = decode8(p, sreg[(kcn) & 1][s]);                         \
            _Pragma("unroll") for (int mt = 0; mt < 4; ++mt)                  \
                acc[mt] = __builtin_amdgcn_mfma_f32_16x16x32_f16(             \
                    afr[mt], b, acc[mt], 0, 0, 0);                            \
        }                                                                     \
    } while (0)

    f32x4 acc[4];
#pragma unroll
    for (int mt = 0; mt < 4; ++mt) acc[mt] = (f32x4){0.f, 0.f, 0.f, 0.f};

    // prologue
    LOADW(0);
    SREGLOAD(0);
    XSTAGE(0);
    WRITEW();
    __syncthreads();

#pragma unroll
    for (int kc = 0; kc < 4; ++kc) {
        if (kc < 3) { LOADW(kc + 1); SREGLOAD(kc + 1); }  // fly under compute
        COMPUTE(kc);
        if (kc < 3) {
            __syncthreads();          // all waves done reading xs[kc]
            XSTAGE(kc + 1);
            WRITEW();                 // wave-private; in-order after COMPUTE
            __syncthreads();          // xs[kc+1] visible
        }
    }
#undef LOADW
#undef WRITEW
#undef SREGLOAD
#undef XSTAGE
#undef COMPUTE

    // epilogue: C/D col(n)=l15 -> nrow, row(m)=quad*4+r (+16*mt)
    if (ATOMIC == 0) {
        float* pb = dst + (size_t)ksp * (MB * OUT_F);
#pragma unroll
        for (int mt = 0; mt < 4; ++mt)
#pragma unroll
            for (int r = 0; r < 4; ++r)
                pb[(size_t)(mt * 16 + quad * 4 + r) * OUT_F + nrow] = acc[mt][r];
    } else {
#pragma unroll
        for (int mt = 0; mt < 4; ++mt)
#pragma unroll
            for (int r = 0; r < 4; ++r)
                atomicAdd(&dst[(size_t)(mt * 16 + quad * 4 + r) * OUT_F + nrow],
                          acc[mt][r]);
    }
}

extern "C" void kernel_launch(void* const* d_in, const int* in_sizes, int n_in,
                              void* d_out, int out_size, void* d_ws, size_t ws_size,
                              hipStream_t stream)
{
    (void)in_sizes; (void)n_in; (void)out_size;
    const float* x      = (const float*)d_in[0];
    const void*  Wp     = (const void*)d_in[1];
    const float* scales = (const float*)d_in[2];
    const float* lora_A = (const float*)d_in[3];
    const float* lora_B = (const float*)d_in[4];
    float* out = (float*)d_out;

    char* ws = (char*)d_ws;
    float* tp      = (float*)ws;                 // 16 KiB (4 kq x 64 m x 16 r)
    uint2* xf      = (uint2*)(ws + 65536);       // 1 MiB fragment-layout fp16 x
    float* partial = (float*)(ws + (2u << 20));  // KSPLIT * 2 MiB = 8 MiB
    const bool full = ws_size >= ((size_t)12 << 20);

    prep_kernel<<<dim3(64, 4), 256, 0, stream>>>(x, lora_A, xf, tp);

    if (full) {
        main8_kernel<0><<<dim3(KSPLIT, 128), 256, 0, stream>>>(
            Wp, scales, (const uint4*)xf, partial);
        finish_kernel<<<(MB * OUT_F / 4) / 256, 256, 0, stream>>>(
            partial, tp, lora_B, out);
    } else {
        lora_kernel<<<(MB * OUT_F / 4) / 256, 256, 0, stream>>>(tp, lora_B, out);
        main8_kernel<1><<<dim3(KSPLIT, 128), 256, 0, stream>>>(
            Wp, scales, (const uint4*)xf, out);
    }
}